// Round 1
// baseline (1320.898 us; speedup 1.0000x reference)
//
#include <hip/hip_runtime.h>
#include <hip/hip_bf16.h>

#define N_NODES 50000
#define N_EDGES 600000
#define DD      128
#define NGRAPHS 64
#define MPAD    50048   // 391*128, multiple of 64/128; padded rows never consumed

typedef __attribute__((ext_vector_type(8))) short  short8;
typedef __attribute__((ext_vector_type(4))) float  float4v;

static __device__ __forceinline__ unsigned short f2bf_rne(float f) {
  unsigned u = __builtin_bit_cast(unsigned, f);
  u = (u + 0x7FFFu + ((u >> 16) & 1u)) >> 16;
  return (unsigned short)u;
}
static __device__ __forceinline__ float bf2f(unsigned short h) {
  unsigned u = ((unsigned)h) << 16;
  return __builtin_bit_cast(float, u);
}
static __device__ __forceinline__ float bflo(unsigned u) { return __builtin_bit_cast(float, u << 16); }
static __device__ __forceinline__ float bfhi(unsigned u) { return __builtin_bit_cast(float, u & 0xFFFF0000u); }

// ---------------- CSR build ----------------
__global__ __launch_bounds__(256) void count_kernel(const int* __restrict__ dst, int* __restrict__ cnt) {
  int i = blockIdx.x * 256 + threadIdx.x;
  if (i < N_EDGES) atomicAdd(&cnt[dst[i]], 1);
}

__global__ __launch_bounds__(1024) void scan_kernel(const int* __restrict__ cnt, int* __restrict__ off,
                                                    int* __restrict__ nxt, float* __restrict__ dis) {
  __shared__ int sm[1024];
  __shared__ int carry;
  if (threadIdx.x == 0) carry = 0;
  __syncthreads();
  for (int base = 0; base < N_NODES; base += 1024) {
    int i = base + (int)threadIdx.x;
    int v = (i < N_NODES) ? cnt[i] : 0;
    sm[threadIdx.x] = v;
    __syncthreads();
    for (int ofs = 1; ofs < 1024; ofs <<= 1) {
      int t = (threadIdx.x >= ofs) ? sm[threadIdx.x - ofs] : 0;
      __syncthreads();
      sm[threadIdx.x] += t;
      __syncthreads();
    }
    if (i < N_NODES) {
      int o = carry + sm[threadIdx.x] - v;   // exclusive
      off[i] = o; nxt[i] = o;
      dis[i] = rsqrtf((float)(v + 1));       // deg includes self-loop
    }
    __syncthreads();
    if (threadIdx.x == 0) carry += sm[1023];
    __syncthreads();
  }
  if (threadIdx.x == 0) off[N_NODES] = carry;
}

__global__ __launch_bounds__(256) void fill_kernel(const int* __restrict__ src, const int* __restrict__ dst,
                                                   int* __restrict__ nxt, const float* __restrict__ dis,
                                                   int* __restrict__ csrc, float* __restrict__ cw) {
  int i = blockIdx.x * 256 + threadIdx.x;
  if (i < N_EDGES) {
    int s = src[i], d = dst[i];
    int pos = atomicAdd(&nxt[d], 1);
    csrc[pos] = s;
    cw[pos] = dis[s] * dis[d];
  }
}

// ---------------- W prep: split bf16 hi/lo, transposed to [conv][n][k] ----------------
__global__ __launch_bounds__(256) void wprep_kernel(const float* __restrict__ W1, const float* __restrict__ W2,
                                                    unsigned short* __restrict__ WH, unsigned short* __restrict__ WL) {
  int idx = blockIdx.x * 256 + threadIdx.x;
  if (idx >= 16 * DD * DD) return;
  int c = idx >> 14;          // conv index 0..15
  int r = idx & 16383;
  int n = r >> 7, k = r & 127;
  const float* W = (c & 1) ? W2 : W1;
  float v = W[((size_t)(c >> 1) << 14) + (size_t)k * DD + n];   // W[l][k][n]
  unsigned short h = f2bf_rne(v);
  WH[idx] = h;
  WL[idx] = f2bf_rne(v - bf2f(h));
}

// ---------------- GEMM: T(bf16)[M x 128] = A(f32)[M x 128] @ W, split-bf16 3-product ----------------
__global__ __launch_bounds__(128) void gemm_split_kernel(const float* __restrict__ A, unsigned short* __restrict__ T,
                                                         const unsigned short* __restrict__ WH,
                                                         const unsigned short* __restrict__ WL, int M) {
  const int lane = threadIdx.x & 63;
  const int wave = threadIdx.x >> 6;
  const int Rbase = blockIdx.x * 64 + wave * 32;
  const int lr = lane & 15;   // A-row / B-col / D-col within fragment
  const int lg = lane >> 4;   // k-group

  float4v acc[2][8];
#pragma unroll
  for (int i = 0; i < 2; ++i)
#pragma unroll
    for (int j = 0; j < 8; ++j) acc[i][j] = (float4v)0.f;

#pragma unroll
  for (int kk = 0; kk < 4; ++kk) {
    const int k0 = kk * 32 + lg * 8;
    short8 ah[2], al[2];
#pragma unroll
    for (int rf = 0; rf < 2; ++rf) {
      int row = Rbase + rf * 16 + lr;
      row = (row < M) ? row : (M - 1);                 // clamp: safe for unpadded x input
      const float* ap = A + (size_t)row * DD + k0;
      float4v x0 = *(const float4v*)ap;
      float4v x1 = *(const float4v*)(ap + 4);
      short8 h, l;
#pragma unroll
      for (int i = 0; i < 4; ++i) {
        unsigned short hb = f2bf_rne(x0[i]);
        h[i] = (short)hb; l[i] = (short)f2bf_rne(x0[i] - bf2f(hb));
      }
#pragma unroll
      for (int i = 0; i < 4; ++i) {
        unsigned short hb = f2bf_rne(x1[i]);
        h[4 + i] = (short)hb; l[4 + i] = (short)f2bf_rne(x1[i] - bf2f(hb));
      }
      ah[rf] = h; al[rf] = l;
    }
#pragma unroll
    for (int n = 0; n < 8; ++n) {
      const size_t wo = (size_t)(n * 16 + lr) * DD + k0;  // Wt[n][k] layout -> contiguous 8 bf16
      short8 bh = *(const short8*)(WH + wo);
      short8 bl = *(const short8*)(WL + wo);
#pragma unroll
      for (int rf = 0; rf < 2; ++rf) {
        acc[rf][n] = __builtin_amdgcn_mfma_f32_16x16x32_bf16(ah[rf], bh, acc[rf][n], 0, 0, 0);
        acc[rf][n] = __builtin_amdgcn_mfma_f32_16x16x32_bf16(al[rf], bh, acc[rf][n], 0, 0, 0);
        acc[rf][n] = __builtin_amdgcn_mfma_f32_16x16x32_bf16(ah[rf], bl, acc[rf][n], 0, 0, 0);
      }
    }
  }
  // D mapping (verified m89): col = lane&15, row = (lane>>4)*4 + j
#pragma unroll
  for (int rf = 0; rf < 2; ++rf) {
#pragma unroll
    for (int j = 0; j < 4; ++j) {
      int row = Rbase + rf * 16 + lg * 4 + j;          // < MPAD always; padded rows never read
      unsigned short* tp = T + (size_t)row * DD;
#pragma unroll
      for (int n = 0; n < 8; ++n) tp[n * 16 + lr] = f2bf_rne(acc[rf][n][j]);
    }
  }
}

// ---------------- Aggregation: h_out(f32) = relu?( b + dis[n]^2*t[n] + sum_e w_e * t[src_e] ) ----------------
__global__ __launch_bounds__(256) void agg_kernel(const unsigned* __restrict__ t, float* __restrict__ ho,
                                                  const int* __restrict__ csrc, const float* __restrict__ cw,
                                                  const int* __restrict__ off, const float* __restrict__ dis,
                                                  const float* __restrict__ bias, int relu) {
  int wid = (int)((blockIdx.x * blockDim.x + threadIdx.x) >> 6);
  int lane = threadIdx.x & 63;
  if (wid >= N_NODES) return;
  int n = __builtin_amdgcn_readfirstlane(wid);
  float dn = dis[n];
  int e0 = off[n], e1 = off[n + 1];

  unsigned sv = t[(size_t)n * 64 + lane];
  float ax = dn * dn * bflo(sv);
  float ay = dn * dn * bfhi(sv);

  int e = e0;
  for (; e + 2 <= e1; e += 2) {
    int s0 = csrc[e], s1 = csrc[e + 1];
    float w0 = cw[e], w1 = cw[e + 1];
    unsigned v0 = t[(size_t)s0 * 64 + lane];
    unsigned v1 = t[(size_t)s1 * 64 + lane];
    ax += w0 * bflo(v0) + w1 * bflo(v1);
    ay += w0 * bfhi(v0) + w1 * bfhi(v1);
  }
  if (e < e1) {
    int s0 = csrc[e];
    float w0 = cw[e];
    unsigned v0 = t[(size_t)s0 * 64 + lane];
    ax += w0 * bflo(v0);
    ay += w0 * bfhi(v0);
  }
  float2 bb = *(const float2*)(bias + 2 * lane);
  ax += bb.x; ay += bb.y;
  if (relu) { ax = fmaxf(ax, 0.f); ay = fmaxf(ay, 0.f); }
  float2 o; o.x = ax; o.y = ay;
  *(float2*)(ho + (size_t)n * DD + 2 * lane) = o;
}

// ---------------- Mean pool over sorted batch ids ----------------
__global__ __launch_bounds__(128) void pool_kernel(const float* __restrict__ h, const int* __restrict__ batch,
                                                   float* __restrict__ out) {
  int g = blockIdx.x;
  int d = threadIdx.x;
  int lo = 0, hi = N_NODES;
  while (lo < hi) { int m = (lo + hi) >> 1; if (batch[m] < g) lo = m + 1; else hi = m; }
  int s = lo;
  lo = s; hi = N_NODES;
  while (lo < hi) { int m = (lo + hi) >> 1; if (batch[m] <= g) lo = m + 1; else hi = m; }
  int e = lo;
  float a = 0.f;
  for (int n = s; n < e; ++n) a += h[(size_t)n * DD + d];
  int c = e - s;
  out[(size_t)g * DD + d] = a / (float)(c > 0 ? c : 1);
}

extern "C" void kernel_launch(void* const* d_in, const int* in_sizes, int n_in,
                              void* d_out, int out_size, void* d_ws, size_t ws_size,
                              hipStream_t stream) {
  const float* x   = (const float*)d_in[0];
  const int*   ei  = (const int*)d_in[1];
  const int*   bat = (const int*)d_in[2];
  const float* W1  = (const float*)d_in[3];
  const float* b1  = (const float*)d_in[4];
  const float* W2  = (const float*)d_in[5];
  const float* b2  = (const float*)d_in[6];
  const int* srcv = ei;
  const int* dstv = ei + N_EDGES;

  char* p = (char*)d_ws;
  auto alloc = [&](size_t bytes) -> char* {
    char* r = p;
    p += (bytes + 255) & ~(size_t)255;
    return r;
  };
  int*            cnt  = (int*)alloc((size_t)N_NODES * 4);
  int*            off  = (int*)alloc((size_t)(N_NODES + 1) * 4);
  int*            nxt  = (int*)alloc((size_t)N_NODES * 4);
  float*          dis  = (float*)alloc((size_t)N_NODES * 4);
  int*            csrc = (int*)alloc((size_t)N_EDGES * 4);
  float*          cw   = (float*)alloc((size_t)N_EDGES * 4);
  unsigned short* WH   = (unsigned short*)alloc((size_t)16 * DD * DD * 2);
  unsigned short* WL   = (unsigned short*)alloc((size_t)16 * DD * DD * 2);
  unsigned short* T    = (unsigned short*)alloc((size_t)MPAD * DD * 2);
  float*          buf0 = (float*)alloc((size_t)MPAD * DD * 4);
  float*          buf1 = (float*)alloc((size_t)MPAD * DD * 4);
  (void)ws_size; (void)in_sizes; (void)n_in; (void)out_size;

  hipMemsetAsync(cnt, 0, (size_t)N_NODES * 4, stream);
  count_kernel<<<(N_EDGES + 255) / 256, 256, 0, stream>>>(dstv, cnt);
  scan_kernel<<<1, 1024, 0, stream>>>(cnt, off, nxt, dis);
  fill_kernel<<<(N_EDGES + 255) / 256, 256, 0, stream>>>(srcv, dstv, nxt, dis, csrc, cw);
  wprep_kernel<<<(16 * DD * DD + 255) / 256, 256, 0, stream>>>(W1, W2, WH, WL);

  const float* hin = x;
  float* bufs[2] = {buf0, buf1};
  for (int c = 0; c < 16; ++c) {
    gemm_split_kernel<<<MPAD / 64, 128, 0, stream>>>(hin, T, WH + (size_t)c * DD * DD, WL + (size_t)c * DD * DD, N_NODES);
    const float* bias = (c & 1) ? (b2 + (size_t)(c >> 1) * DD) : (b1 + (size_t)(c >> 1) * DD);
    float* ho = bufs[c & 1];
    agg_kernel<<<(N_NODES * 64) / 256, 256, 0, stream>>>((const unsigned*)T, ho, csrc, cw, off, dis, bias, (c & 1) ? 0 : 1);
    hin = ho;
  }
  pool_kernel<<<NGRAPHS, 128, 0, stream>>>(bufs[1], bat, (float*)d_out);
}

// Round 2
// 990.834 us; speedup vs baseline: 1.3331x; 1.3331x over previous
//
#include <hip/hip_runtime.h>
#include <hip/hip_bf16.h>

#define N_NODES 50000
#define N_EDGES 600000
#define DD      128
#define NGRAPHS 64
#define MPAD    50048   // 391*128, multiple of 64/128; padded rows never consumed
#define SCB     512
#define NSCB    ((N_NODES + SCB - 1) / SCB)   // 98
#define PB_NODES 64

typedef __attribute__((ext_vector_type(8))) short  short8;
typedef __attribute__((ext_vector_type(4))) float  float4v;

static __device__ __forceinline__ unsigned short f2bf_rne(float f) {
  unsigned u = __builtin_bit_cast(unsigned, f);
  u = (u + 0x7FFFu + ((u >> 16) & 1u)) >> 16;
  return (unsigned short)u;
}
static __device__ __forceinline__ float bf2f(unsigned short h) {
  unsigned u = ((unsigned)h) << 16;
  return __builtin_bit_cast(float, u);
}
static __device__ __forceinline__ float bflo(unsigned u) { return __builtin_bit_cast(float, u << 16); }
static __device__ __forceinline__ float bfhi(unsigned u) { return __builtin_bit_cast(float, u & 0xFFFF0000u); }

// ---------------- CSR build ----------------
__global__ __launch_bounds__(256) void count_kernel(const int* __restrict__ dst, int* __restrict__ cnt) {
  int i = blockIdx.x * 256 + threadIdx.x;
  if (i < N_EDGES) atomicAdd(&cnt[dst[i]], 1);
}

// block-local exclusive scan of cnt -> loc, block totals -> bsum
__global__ __launch_bounds__(SCB) void scanA_kernel(const int* __restrict__ cnt, int* __restrict__ loc,
                                                    int* __restrict__ bsum) {
  __shared__ int sm[SCB];
  int t = threadIdx.x;
  int i = blockIdx.x * SCB + t;
  int v = (i < N_NODES) ? cnt[i] : 0;
  sm[t] = v;
  __syncthreads();
  for (int ofs = 1; ofs < SCB; ofs <<= 1) {
    int u = (t >= ofs) ? sm[t - ofs] : 0;
    __syncthreads();
    sm[t] += u;
    __syncthreads();
  }
  if (i < N_NODES) loc[i] = sm[t] - v;
  if (t == SCB - 1) bsum[blockIdx.x] = sm[t];
}

__global__ __launch_bounds__(64) void scanB_kernel(const int* __restrict__ bsum, int* __restrict__ boff,
                                                   int* __restrict__ off_last) {
  if (threadIdx.x == 0) {
    int a = 0;
    for (int b = 0; b < NSCB; ++b) { boff[b] = a; a += bsum[b]; }
    *off_last = a;
  }
}

__global__ __launch_bounds__(SCB) void scanC_kernel(const int* __restrict__ loc, const int* __restrict__ boff,
                                                    const int* __restrict__ cnt, int* __restrict__ off,
                                                    int* __restrict__ nxt, float* __restrict__ dis) {
  int i = blockIdx.x * SCB + threadIdx.x;
  if (i < N_NODES) {
    int o = loc[i] + boff[blockIdx.x];
    off[i] = o; nxt[i] = o;
    dis[i] = rsqrtf((float)(cnt[i] + 1));   // deg includes self-loop
  }
}

__global__ __launch_bounds__(256) void fill_kernel(const int* __restrict__ src, const int* __restrict__ dst,
                                                   int* __restrict__ nxt, const float* __restrict__ dis,
                                                   int2* __restrict__ edge) {
  int i = blockIdx.x * 256 + threadIdx.x;
  if (i < N_EDGES) {
    int s = src[i], d = dst[i];
    int pos = atomicAdd(&nxt[d], 1);
    int2 p; p.x = s; p.y = __float_as_int(dis[s] * dis[d]);
    edge[pos] = p;
  }
}

// ---------------- W prep: split bf16 hi/lo, transposed to [conv][n][k] ----------------
__global__ __launch_bounds__(256) void wprep_kernel(const float* __restrict__ W1, const float* __restrict__ W2,
                                                    unsigned short* __restrict__ WH, unsigned short* __restrict__ WL) {
  int idx = blockIdx.x * 256 + threadIdx.x;
  if (idx >= 16 * DD * DD) return;
  int c = idx >> 14;          // conv index 0..15
  int r = idx & 16383;
  int n = r >> 7, k = r & 127;
  const float* W = (c & 1) ? W2 : W1;
  float v = W[((size_t)(c >> 1) << 14) + (size_t)k * DD + n];   // W[l][k][n]
  unsigned short h = f2bf_rne(v);
  WH[idx] = h;
  WL[idx] = f2bf_rne(v - bf2f(h));
}

// ---------------- GEMM: T(bf16)[M x 128] = A(f32)[M x 128] @ W, split-bf16 3-product ----------------
__global__ __launch_bounds__(128) void gemm_split_kernel(const float* __restrict__ A, unsigned short* __restrict__ T,
                                                         const unsigned short* __restrict__ WH,
                                                         const unsigned short* __restrict__ WL, int M) {
  const int lane = threadIdx.x & 63;
  const int wave = threadIdx.x >> 6;
  const int Rbase = blockIdx.x * 64 + wave * 32;
  const int lr = lane & 15;   // A-row / B-col / D-col within fragment
  const int lg = lane >> 4;   // k-group

  float4v acc[2][8];
#pragma unroll
  for (int i = 0; i < 2; ++i)
#pragma unroll
    for (int j = 0; j < 8; ++j) acc[i][j] = (float4v)0.f;

#pragma unroll
  for (int kk = 0; kk < 4; ++kk) {
    const int k0 = kk * 32 + lg * 8;
    short8 ah[2], al[2];
#pragma unroll
    for (int rf = 0; rf < 2; ++rf) {
      int row = Rbase + rf * 16 + lr;
      row = (row < M) ? row : (M - 1);                 // clamp: safe for unpadded x input
      const float* ap = A + (size_t)row * DD + k0;
      float4v x0 = *(const float4v*)ap;
      float4v x1 = *(const float4v*)(ap + 4);
      short8 h, l;
#pragma unroll
      for (int i = 0; i < 4; ++i) {
        unsigned short hb = f2bf_rne(x0[i]);
        h[i] = (short)hb; l[i] = (short)f2bf_rne(x0[i] - bf2f(hb));
      }
#pragma unroll
      for (int i = 0; i < 4; ++i) {
        unsigned short hb = f2bf_rne(x1[i]);
        h[4 + i] = (short)hb; l[4 + i] = (short)f2bf_rne(x1[i] - bf2f(hb));
      }
      ah[rf] = h; al[rf] = l;
    }
#pragma unroll
    for (int n = 0; n < 8; ++n) {
      const size_t wo = (size_t)(n * 16 + lr) * DD + k0;  // Wt[n][k] layout -> contiguous 8 bf16
      short8 bh = *(const short8*)(WH + wo);
      short8 bl = *(const short8*)(WL + wo);
#pragma unroll
      for (int rf = 0; rf < 2; ++rf) {
        acc[rf][n] = __builtin_amdgcn_mfma_f32_16x16x32_bf16(ah[rf], bh, acc[rf][n], 0, 0, 0);
        acc[rf][n] = __builtin_amdgcn_mfma_f32_16x16x32_bf16(al[rf], bh, acc[rf][n], 0, 0, 0);
        acc[rf][n] = __builtin_amdgcn_mfma_f32_16x16x32_bf16(ah[rf], bl, acc[rf][n], 0, 0, 0);
      }
    }
  }
  // D mapping (verified m89): col = lane&15, row = (lane>>4)*4 + j
#pragma unroll
  for (int rf = 0; rf < 2; ++rf) {
#pragma unroll
    for (int j = 0; j < 4; ++j) {
      int row = Rbase + rf * 16 + lg * 4 + j;          // < MPAD always; padded rows never read
      unsigned short* tp = T + (size_t)row * DD;
#pragma unroll
      for (int n = 0; n < 8; ++n) tp[n * 16 + lr] = f2bf_rne(acc[rf][n][j]);
    }
  }
}

// ---------------- Aggregation: h_out(f32) = relu?( b + dis[n]^2*t[n] + sum_e w_e * t[src_e] ) ----------------
__global__ __launch_bounds__(256) void agg_kernel(const unsigned* __restrict__ t, float* __restrict__ ho,
                                                  const int2* __restrict__ edge,
                                                  const int* __restrict__ off, const float* __restrict__ dis,
                                                  const float* __restrict__ bias, int relu) {
  int wid = (int)((blockIdx.x * blockDim.x + threadIdx.x) >> 6);
  int lane = threadIdx.x & 63;
  if (wid >= N_NODES) return;
  int n = __builtin_amdgcn_readfirstlane(wid);
  float dn = dis[n];
  int e0 = off[n], e1 = off[n + 1];

  unsigned sv = t[(size_t)n * 64 + lane];
  float axA = dn * dn * bflo(sv), ayA = dn * dn * bfhi(sv);
  float axB = 0.f, ayB = 0.f;

  int e = e0;
  for (; e + 4 <= e1; e += 4) {
    int2 p0 = edge[e], p1 = edge[e + 1], p2 = edge[e + 2], p3 = edge[e + 3];
    unsigned v0 = t[(size_t)p0.x * 64 + lane];
    unsigned v1 = t[(size_t)p1.x * 64 + lane];
    unsigned v2 = t[(size_t)p2.x * 64 + lane];
    unsigned v3 = t[(size_t)p3.x * 64 + lane];
    float w0 = __int_as_float(p0.y), w1 = __int_as_float(p1.y);
    float w2 = __int_as_float(p2.y), w3 = __int_as_float(p3.y);
    axA += w0 * bflo(v0) + w2 * bflo(v2);
    ayA += w0 * bfhi(v0) + w2 * bfhi(v2);
    axB += w1 * bflo(v1) + w3 * bflo(v3);
    ayB += w1 * bfhi(v1) + w3 * bfhi(v3);
  }
  for (; e < e1; ++e) {
    int2 p0 = edge[e];
    unsigned v0 = t[(size_t)p0.x * 64 + lane];
    float w0 = __int_as_float(p0.y);
    axA += w0 * bflo(v0);
    ayA += w0 * bfhi(v0);
  }
  float2 bb = *(const float2*)(bias + 2 * lane);
  float ax = axA + axB + bb.x, ay = ayA + ayB + bb.y;
  if (relu) { ax = fmaxf(ax, 0.f); ay = fmaxf(ay, 0.f); }
  float2 o; o.x = ax; o.y = ay;
  *(float2*)(ho + (size_t)n * DD + 2 * lane) = o;
}

// ---------------- Mean pool, two-stage ----------------
__global__ __launch_bounds__(128) void pool1_kernel(const float* __restrict__ h, const int* __restrict__ batch,
                                                    float* __restrict__ gsum, int* __restrict__ gcnt) {
  int d = threadIdx.x;
  int n0 = blockIdx.x * PB_NODES;
  if (n0 >= N_NODES) return;
  int n1 = n0 + PB_NODES; if (n1 > N_NODES) n1 = N_NODES;
  float acc = 0.f;
  int gid = batch[n0];
  int segstart = n0;
  for (int n = n0; n < n1; ++n) {
    int g = batch[n];
    if (g != gid) {
      atomicAdd(&gsum[gid * DD + d], acc);
      if (d == 0) atomicAdd(&gcnt[gid], n - segstart);
      acc = 0.f; gid = g; segstart = n;
    }
    acc += h[(size_t)n * DD + d];
  }
  atomicAdd(&gsum[gid * DD + d], acc);
  if (d == 0) atomicAdd(&gcnt[gid], n1 - segstart);
}

__global__ __launch_bounds__(128) void pool2_kernel(const float* __restrict__ gsum, const int* __restrict__ gcnt,
                                                    float* __restrict__ out) {
  int g = blockIdx.x, d = threadIdx.x;
  int c = gcnt[g];
  out[(size_t)g * DD + d] = gsum[(size_t)g * DD + d] / (float)(c > 0 ? c : 1);
}

extern "C" void kernel_launch(void* const* d_in, const int* in_sizes, int n_in,
                              void* d_out, int out_size, void* d_ws, size_t ws_size,
                              hipStream_t stream) {
  const float* x   = (const float*)d_in[0];
  const int*   ei  = (const int*)d_in[1];
  const int*   bat = (const int*)d_in[2];
  const float* W1  = (const float*)d_in[3];
  const float* b1  = (const float*)d_in[4];
  const float* W2  = (const float*)d_in[5];
  const float* b2  = (const float*)d_in[6];
  const int* srcv = ei;
  const int* dstv = ei + N_EDGES;

  char* p = (char*)d_ws;
  auto alloc = [&](size_t bytes) -> char* {
    char* r = p;
    p += (bytes + 255) & ~(size_t)255;
    return r;
  };
  int*            cnt  = (int*)alloc((size_t)N_NODES * 4);
  int*            off  = (int*)alloc((size_t)(N_NODES + 1) * 4);
  int*            nxt  = (int*)alloc((size_t)N_NODES * 4);
  float*          dis  = (float*)alloc((size_t)N_NODES * 4);
  int*            loc  = (int*)alloc((size_t)N_NODES * 4);
  int*            bsum = (int*)alloc((size_t)NSCB * 4);
  int*            boff = (int*)alloc((size_t)NSCB * 4);
  int2*           edge = (int2*)alloc((size_t)N_EDGES * 8);
  unsigned short* WH   = (unsigned short*)alloc((size_t)16 * DD * DD * 2);
  unsigned short* WL   = (unsigned short*)alloc((size_t)16 * DD * DD * 2);
  unsigned short* T    = (unsigned short*)alloc((size_t)MPAD * DD * 2);
  float*          buf0 = (float*)alloc((size_t)MPAD * DD * 4);
  float*          buf1 = (float*)alloc((size_t)MPAD * DD * 4);
  float*          gsum = (float*)alloc((size_t)NGRAPHS * DD * 4);
  int*            gcnt = (int*)alloc((size_t)NGRAPHS * 4);
  (void)ws_size; (void)in_sizes; (void)n_in; (void)out_size;

  hipMemsetAsync(cnt, 0, (size_t)N_NODES * 4, stream);
  hipMemsetAsync(gsum, 0, (size_t)NGRAPHS * DD * 4 + 256, stream);  // gsum + gcnt (adjacent, 256-aligned)
  count_kernel<<<(N_EDGES + 255) / 256, 256, 0, stream>>>(dstv, cnt);
  scanA_kernel<<<NSCB, SCB, 0, stream>>>(cnt, loc, bsum);
  scanB_kernel<<<1, 64, 0, stream>>>(bsum, boff, &off[N_NODES]);
  scanC_kernel<<<NSCB, SCB, 0, stream>>>(loc, boff, cnt, off, nxt, dis);
  fill_kernel<<<(N_EDGES + 255) / 256, 256, 0, stream>>>(srcv, dstv, nxt, dis, edge);
  wprep_kernel<<<(16 * DD * DD + 255) / 256, 256, 0, stream>>>(W1, W2, WH, WL);

  const float* hin = x;
  float* bufs[2] = {buf0, buf1};
  for (int c = 0; c < 16; ++c) {
    gemm_split_kernel<<<MPAD / 64, 128, 0, stream>>>(hin, T, WH + (size_t)c * DD * DD, WL + (size_t)c * DD * DD, N_NODES);
    const float* bias = (c & 1) ? (b2 + (size_t)(c >> 1) * DD) : (b1 + (size_t)(c >> 1) * DD);
    float* ho = bufs[c & 1];
    agg_kernel<<<(N_NODES * 64) / 256, 256, 0, stream>>>((const unsigned*)T, ho, edge, off, dis, bias, (c & 1) ? 0 : 1);
    hin = ho;
  }
  pool1_kernel<<<(N_NODES + PB_NODES - 1) / PB_NODES, 128, 0, stream>>>(bufs[1], bat, gsum, gcnt);
  pool2_kernel<<<NGRAPHS, 128, 0, stream>>>(gsum, gcnt, (float*)d_out);
}